// Round 2
// 435.686 us; speedup vs baseline: 1.3797x; 1.3797x over previous
//
#include <hip/hip_runtime.h>
#include <hip/hip_bf16.h>

// Attention fwd: B=4 H=16 S=2048 D=128, fp32 in/out, scale = 128^-0.5.
// V -> VT[bh][d][s] bf16 in d_ws (32 MB). If ws_size >= 64 MB, K is also
// pre-converted to bf16 (Kb, +32 MB) and the hot loop stages it with pure
// uint4 copies; otherwise K is converted in-loop via v_cvt_pk_bf16_f32.
// fattn: 256 thr = 4 waves, 64 Q-rows/block, KV tiles of 64 keys.
// Q held in registers (pre-scaled by scale*log2e). Defer-max softmax:
// fast path has NO cross-lane reductions (local max + __any ballot only);
// l is accumulated as per-lane partials, reduced once in the epilogue.
// P written as packed b32 pairs (shfl_xor(1) + cvt_pk) -> bank-conflict free.
// LDS = 45,056 B -> 3 blocks/CU (was 62,464 -> 2).

#define SEQ 2048
#define DH  128
#define NBH 64          // B*H
#define BM  64          // Q rows per block
#define BN  64          // keys per KV iteration
#define QK_LD 136       // bf16 elems per row for K tile (128+8): 272B rows
#define VT_LD 72        // (64+8): 144B rows
#define P_LD  72
#define THR 8.0f        // defer-max threshold (exp2 domain): P <= 2^8

typedef __attribute__((ext_vector_type(8))) short short8;
typedef __attribute__((ext_vector_type(4))) float f32x4;

#if __has_builtin(__builtin_amdgcn_exp2f)
#define EXP2F(x) __builtin_amdgcn_exp2f(x)
#else
#define EXP2F(x) exp2f(x)
#endif

// softmax scale folded with log2(e), pre-applied to Q at load time
#define CS (0.08838834764831845f * 1.44269504088896340736f)

__device__ __forceinline__ unsigned int pk_bf16(float lo, float hi) {
    union { __hip_bfloat162 h; unsigned int u; } cv;
    cv.h = __float22bfloat162_rn(make_float2(lo, hi));   // v_cvt_pk_bf16_f32
    return cv.u;
}

// ---- V transpose + bf16 convert: V[bh][s][d] (f32) -> VT[bh][d][s] (bf16) ----
__global__ __launch_bounds__(256) void transpose_v_kernel(
        const float* __restrict__ v, unsigned short* __restrict__ vt) {
    __shared__ float tile[64][65];          // +1 pad: transposed reads 2-way free
    const int bh = blockIdx.z;
    const int s0 = blockIdx.x * 64;
    const int d0 = blockIdx.y * 64;
    const int tid = threadIdx.x;
    const float* src = v + ((size_t)bh * SEQ + s0) * DH + d0;
#pragma unroll
    for (int i = 0; i < 4; ++i) {
        int id  = tid + 256 * i;
        int row = id >> 4;                  // 0..63 key
        int c4  = (id & 15) << 2;           // 0..60 d offset
        float4 val = *reinterpret_cast<const float4*>(src + row * DH + c4);
        tile[row][c4 + 0] = val.x;
        tile[row][c4 + 1] = val.y;
        tile[row][c4 + 2] = val.z;
        tile[row][c4 + 3] = val.w;
    }
    __syncthreads();
    unsigned short* dst = vt + ((size_t)bh * DH + d0) * SEQ + s0;
#pragma unroll
    for (int i = 0; i < 2; ++i) {
        int id = tid + 256 * i;
        int dd = id >> 3;                   // 0..63 d row
        int kc = (id & 7) << 3;             // key chunk of 8
        uint4 pk;
        unsigned int* pw = reinterpret_cast<unsigned int*>(&pk);
#pragma unroll
        for (int j = 0; j < 4; ++j)
            pw[j] = pk_bf16(tile[kc + 2 * j][dd], tile[kc + 2 * j + 1][dd]);
        *reinterpret_cast<uint4*>(dst + (size_t)dd * SEQ + kc) = pk;   // 16B coalesced
    }
}

// ---- K convert: K[bh][s][d] f32 -> bf16 (same layout), pure streaming ----
__global__ __launch_bounds__(256) void convert_k_kernel(
        const float* __restrict__ k, unsigned short* __restrict__ kb) {
    size_t base = ((size_t)blockIdx.x * 256 + threadIdx.x) * 8;
    float4 a = *reinterpret_cast<const float4*>(k + base);
    float4 b = *reinterpret_cast<const float4*>(k + base + 4);
    uint4 o;
    o.x = pk_bf16(a.x, a.y);
    o.y = pk_bf16(a.z, a.w);
    o.z = pk_bf16(b.x, b.y);
    o.w = pk_bf16(b.z, b.w);
    *reinterpret_cast<uint4*>(kb + base) = o;
}

// ---- flash attention ----
template<bool KPRE>
__global__ __launch_bounds__(256, 3) void fattn_kernel(
        const float* __restrict__ q, const float* __restrict__ kf,
        const unsigned short* __restrict__ kb,
        const unsigned short* __restrict__ vt, float* __restrict__ out) {
    __shared__ unsigned short Ks[BN * QK_LD];   // [key][d]
    __shared__ unsigned short Vs[DH * VT_LD];   // [d][key]  (transposed V tile)
    __shared__ unsigned short Ps[BM * P_LD];    // [q_row][key]

    // XCD swizzle: cluster the 32 q-blocks of each bh on one XCD (2048 = 8*256)
    const int wid = ((blockIdx.x & 7) << 8) | (blockIdx.x >> 3);
    const int bh  = wid >> 5;
    const int q0  = (wid & 31) * BM;
    const int tid  = threadIdx.x;
    const int w    = tid >> 6;      // wave 0..3
    const int lane = tid & 63;
    const int l15  = lane & 15;
    const int quad = lane >> 4;

    // ---- Q (16 rows for this wave) into registers, scaled by CS, bf16 ----
    short8 qf[4];
    {
        const float* qptr = q + ((size_t)bh * SEQ + q0 + w * 16 + l15) * DH + quad * 8;
#pragma unroll
        for (int kk = 0; kk < 4; ++kk) {
            float4 x = *reinterpret_cast<const float4*>(qptr + kk * 32);
            float4 y = *reinterpret_cast<const float4*>(qptr + kk * 32 + 4);
            union { short8 s; uint4 u; } cv;
            cv.u.x = pk_bf16(x.x * CS, x.y * CS);
            cv.u.y = pk_bf16(x.z * CS, x.w * CS);
            cv.u.z = pk_bf16(y.x * CS, y.y * CS);
            cv.u.w = pk_bf16(y.z * CS, y.w * CS);
            qf[kk] = cv.s;
        }
    }

    f32x4 o[8];
#pragma unroll
    for (int t = 0; t < 8; ++t) o[t] = (f32x4){0.f, 0.f, 0.f, 0.f};
    float mrow[4] = {-1e30f, -1e30f, -1e30f, -1e30f};
    float lrow[4] = {0.f, 0.f, 0.f, 0.f};   // per-lane PARTIAL sums (reduced in epilogue)

    const float*          kfp = kf + (size_t)bh * SEQ * DH;
    const unsigned short* kbp = kb + (size_t)bh * SEQ * DH;
    const unsigned short* vptr = vt + (size_t)bh * DH * SEQ;

    unsigned int* Ps32 = reinterpret_cast<unsigned int*>(Ps);
    const int prow_base = w * 16 + quad * 4;
    // within-row dword offset for packed P writes: evens own t0/t2, odds t1/t3
    const int pdw = (l15 & 1) ? (8 + (l15 >> 1)) : (l15 >> 1);

    for (int kt = 0; kt < SEQ / BN; ++kt) {
        const int k0 = kt * BN;
        // ---- stage K tile (64 keys x 128 d) ----
        if (KPRE) {     // already bf16: pure 16B copies
#pragma unroll
            for (int i = 0; i < 4; ++i) {
                int id  = tid + 256 * i;
                int row = id >> 4;              // 0..63
                int c   = (id & 15) << 3;       // 0..120
                *reinterpret_cast<uint4*>(&Ks[row * QK_LD + c]) =
                    *reinterpret_cast<const uint4*>(kbp + (size_t)(k0 + row) * DH + c);
            }
        } else {        // f32 -> bf16 via cvt_pk (2 VALU per 4 floats)
#pragma unroll
            for (int i = 0; i < 8; ++i) {
                int id  = tid + 256 * i;
                int row = id >> 5;              // 0..63
                int c4  = (id & 31) << 2;       // 0..124
                float4 val = *reinterpret_cast<const float4*>(kfp + (size_t)(k0 + row) * DH + c4);
                uint2 pk;
                pk.x = pk_bf16(val.x, val.y);
                pk.y = pk_bf16(val.z, val.w);
                *reinterpret_cast<uint2*>(&Ks[row * QK_LD + c4]) = pk;
            }
        }
        // ---- stage VT tile (128 d x 64 keys), already bf16 ----
#pragma unroll
        for (int i = 0; i < 4; ++i) {
            int id = tid + 256 * i;
            int dd = id >> 3;               // 0..127
            int kc = (id & 7) << 3;         // 0..56
            *reinterpret_cast<uint4*>(&Vs[dd * VT_LD + kc]) =
                *reinterpret_cast<const uint4*>(vptr + (size_t)dd * SEQ + k0 + kc);
        }
        __syncthreads();

        // ---- S = Q K^T (pre-scaled): wave w computes rows [w*16,w*16+16) x 64 keys
        f32x4 acc[4];
#pragma unroll
        for (int t = 0; t < 4; ++t) acc[t] = (f32x4){0.f, 0.f, 0.f, 0.f};
#pragma unroll
        for (int kk = 0; kk < 4; ++kk) {
            const int koff = kk * 32 + quad * 8;
#pragma unroll
            for (int t = 0; t < 4; ++t) {
                short8 b = *reinterpret_cast<const short8*>(&Ks[(t * 16 + l15) * QK_LD + koff]);
                acc[t] = __builtin_amdgcn_mfma_f32_16x16x32_bf16(qf[kk], b, acc[t], 0, 0, 0);
            }
        }

        // ---- defer-max: fast path needs no cross-lane reduction at all ----
        float lm[4];
#pragma unroll
        for (int r = 0; r < 4; ++r)
            lm[r] = fmaxf(fmaxf(acc[0][r], acc[1][r]), fmaxf(acc[2][r], acc[3][r]));
        float need = fmaxf(fmaxf(lm[0] - mrow[0], lm[1] - mrow[1]),
                           fmaxf(lm[2] - mrow[2], lm[3] - mrow[3]));
        if (__any(need > THR)) {
            // slow path (first tile + rare growth): full row max, rescale o/l
#pragma unroll
            for (int r = 0; r < 4; ++r) {
                float mx = lm[r];
#pragma unroll
                for (int off = 1; off < 16; off <<= 1)
                    mx = fmaxf(mx, __shfl_xor(mx, off));
                float mnew  = fmaxf(mrow[r], mx);
                float alpha = EXP2F(mrow[r] - mnew);
                mrow[r] = mnew;
                lrow[r] *= alpha;
#pragma unroll
                for (int t = 0; t < 8; ++t) o[t][r] *= alpha;
            }
        }

        // ---- P = exp2(S - m) (bounded by 2^8), packed conflict-free writes ----
#pragma unroll
        for (int r = 0; r < 4; ++r) {
            float p0 = EXP2F(acc[0][r] - mrow[r]);
            float p1 = EXP2F(acc[1][r] - mrow[r]);
            float p2 = EXP2F(acc[2][r] - mrow[r]);
            float p3 = EXP2F(acc[3][r] - mrow[r]);
            lrow[r] += (p0 + p1) + (p2 + p3);
            unsigned int a01 = pk_bf16(p0, p1);
            unsigned int a23 = pk_bf16(p2, p3);
            unsigned int s01 = __shfl_xor((int)a01, 1);
            unsigned int s23 = __shfl_xor((int)a23, 1);
            unsigned int w0, w1;
            if (l15 & 1) {  // odd lanes own t1/t3 dwords: low = partner's, high = own
                w0 = (s01 >> 16) | (a01 & 0xffff0000u);
                w1 = (s23 >> 16) | (a23 & 0xffff0000u);
            } else {        // even lanes own t0/t2 dwords: low = own, high = partner's
                w0 = (a01 & 0xffffu) | (s01 << 16);
                w1 = (a23 & 0xffffu) | (s23 << 16);
            }
            const int dw = (prow_base + r) * (P_LD / 2) + pdw;
            Ps32[dw]      = w0;   // cols {t0|t1}
            Ps32[dw + 16] = w1;   // cols {t2|t3}
        }

        // ---- O += P V : A-frag from own P rows, B-frag from VT tile ----
#pragma unroll
        for (int kk = 0; kk < 2; ++kk) {
            const int koff = kk * 32 + quad * 8;
            short8 a = *reinterpret_cast<const short8*>(&Ps[(w * 16 + l15) * P_LD + koff]);
#pragma unroll
            for (int t = 0; t < 8; ++t) {
                short8 b = *reinterpret_cast<const short8*>(&Vs[(t * 16 + l15) * VT_LD + koff]);
                o[t] = __builtin_amdgcn_mfma_f32_16x16x32_bf16(a, b, o[t], 0, 0, 0);
            }
        }
        __syncthreads();   // protect K/V tiles before next iteration's staging
    }

    // ---- epilogue: reduce distributed l, normalize, store fp32 ----
#pragma unroll
    for (int r = 0; r < 4; ++r) {
#pragma unroll
        for (int off = 1; off < 16; off <<= 1)
            lrow[r] += __shfl_xor(lrow[r], off);
    }
    float* obase = out + ((size_t)bh * SEQ + q0) * DH;
#pragma unroll
    for (int r = 0; r < 4; ++r) {
        float inv = 1.0f / lrow[r];
        int row = w * 16 + quad * 4 + r;
#pragma unroll
        for (int t = 0; t < 8; ++t)
            obase[(size_t)row * DH + t * 16 + l15] = o[t][r] * inv;
    }
}

extern "C" void kernel_launch(void* const* d_in, const int* in_sizes, int n_in,
                              void* d_out, int out_size, void* d_ws, size_t ws_size,
                              hipStream_t stream) {
    const float* q = (const float*)d_in[0];
    const float* k = (const float*)d_in[1];
    const float* v = (const float*)d_in[2];
    float* out = (float*)d_out;
    unsigned short* vt = (unsigned short*)d_ws;                   // 32 MB

    transpose_v_kernel<<<dim3(SEQ / 64, DH / 64, NBH), dim3(256), 0, stream>>>(v, vt);

    const size_t vt_elems = (size_t)NBH * SEQ * DH;               // 16M shorts
    if (ws_size >= 2 * vt_elems * sizeof(unsigned short)) {
        // room for a bf16 K copy: pre-convert once, hot loop does pure copies
        unsigned short* kbuf = vt + vt_elems;
        convert_k_kernel<<<dim3((NBH * SEQ * DH) / (256 * 8)), dim3(256), 0, stream>>>(k, kbuf);
        fattn_kernel<true><<<dim3(SEQ / BM * NBH), dim3(256), 0, stream>>>(q, nullptr, kbuf, vt, out);
    } else {
        // fallback: convert K in-loop with cvt_pk (cheap)
        fattn_kernel<false><<<dim3(SEQ / BM * NBH), dim3(256), 0, stream>>>(q, k, nullptr, vt, out);
    }
}